// Round 2
// baseline (204.893 us; speedup 1.0000x reference)
//
#include <hip/hip_runtime.h>
#include <hip/hip_bf16.h>

// Problem constants
#define BATCH  16384
#define DIM    512
#define NLAYER 3
#define NEXP   4
#define RANK   128

typedef __bf16 bf16_t;
typedef bf16_t bf16x8 __attribute__((ext_vector_type(8)));
typedef bf16_t bf16x4 __attribute__((ext_vector_type(4)));
typedef float  f32x4  __attribute__((ext_vector_type(4)));

__device__ __forceinline__ float tanh_fast(float x) {
    float e = __expf(2.0f * x);
    return 1.0f - 2.0f * __builtin_amdgcn_rcpf(e + 1.0f);
}

// Async global->LDS: stage a [128][64] bf16 tile (16 KB), linear layout.
// LDS dest is wave-uniform base; HW adds lane*16. Global src is per-lane.
__device__ __forceinline__ void stage64(const bf16_t* __restrict__ g_tile,
                                        size_t g_stride_b,   // global row stride, bytes
                                        bf16_t* l_tile, int tid) {
    const int lane = tid & 63;
    const int wave = tid >> 6;
    #pragma unroll
    for (int i = 0; i < 4; ++i) {
        const int chunk = i * 4 + wave;              // 0..15, 1 KB each
        const int o     = chunk * 1024 + lane * 16;  // byte offset in tile
        const int row   = o >> 7;                    // 128 B per row
        const int colb  = o & 127;
        const char* g = (const char*)g_tile + (size_t)row * g_stride_b + colb;
        char* l = (char*)l_tile + chunk * 1024;      // wave-uniform
        __builtin_amdgcn_global_load_lds(
            (const __attribute__((address_space(1))) void*)g,
            (__attribute__((address_space(3))) void*)l, 16, 0, 0);
    }
}

// ---------------- prep kernels ----------------

// vectorized f32 -> bf16, 8 elems/thread (n must be multiple of 8)
__global__ void convert8(const float* __restrict__ in,
                         bf16_t* __restrict__ out, int n8) {
    int i = blockIdx.x * 256 + threadIdx.x;
    if (i >= n8) return;
    float4 a = *(const float4*)(in + (size_t)i * 8);
    float4 b = *(const float4*)(in + (size_t)i * 8 + 4);
    bf16x8 v = { (bf16_t)a.x, (bf16_t)a.y, (bf16_t)a.z, (bf16_t)a.w,
                 (bf16_t)b.x, (bf16_t)b.y, (bf16_t)b.z, (bf16_t)b.w };
    *(bf16x8*)(out + (size_t)i * 8) = v;
}

// Vt[le][r][d] = Vs[le][d][r]
__global__ void transpose_v(const float* __restrict__ Vs,
                            bf16_t* __restrict__ Vt) {
    int i = blockIdx.x * 256 + threadIdx.x;      // < 12*128*512
    int d  = i & (DIM - 1);
    int r  = (i >> 9) & (RANK - 1);
    int le = i >> 16;
    Vt[i] = (bf16_t)Vs[((size_t)le * DIM + d) * RANK + r];
}

// ---------------- k1: XC = tanh( tanh(XL @ V_e) @ C_e^T ) ----------------
// grid (BATCH/128, NEXP), block 256 (4 waves, 2x2 of 64x64)

__global__ __launch_bounds__(256, 2)
void k1_vc(const bf16_t* __restrict__ Ab,    // xl bf16 (B, 512)
           const bf16_t* __restrict__ Vt,    // [E][R][D] this layer
           const bf16_t* __restrict__ Cl,    // [E][R][R] this layer
           bf16_t* __restrict__ XC)          // (B, 512) bf16 out
{
    const int m0   = blockIdx.x * 128;
    const int e    = blockIdx.y;
    const int tid  = threadIdx.x;
    const int lane = tid & 63;
    const int wave = tid >> 6;
    const int wm = wave >> 1, wn = wave & 1;
    const int lr = lane & 15;
    const int lg = lane >> 4;

    __shared__ __align__(16) char smem[69632];
    bf16_t* As = (bf16_t*)smem;              // [128][64] linear, phase 1
    bf16_t* Bs = (bf16_t*)(smem + 16384);    // [128][64] linear, phase 1
    bf16_t* Xs = (bf16_t*)smem;              // [128][136] phase 2 (XV as A)
    bf16_t* Cs = (bf16_t*)(smem + 34816);    // [128][136] phase 2 (C^T)

    const bf16_t* Ve = Vt + (size_t)e * RANK * DIM;

    f32x4 acc[4][4] = {};

    // ---- phase 1: XV = XL @ V_e  (M=128, N=128, K=512) ----
    for (int kc = 0; kc < DIM; kc += 64) {
        stage64(Ab + (size_t)m0 * DIM + kc, DIM * 2, As, tid);
        stage64(Ve + kc,                    DIM * 2, Bs, tid);
        __syncthreads();   // drains vmcnt before barrier
        #pragma unroll
        for (int ks = 0; ks < 64; ks += 32) {
            bf16x8 af[4], bfv[4];
            #pragma unroll
            for (int mi = 0; mi < 4; ++mi)
                af[mi] = *(const bf16x8*)(As + (wm*64 + mi*16 + lr) * 64 + ks + lg*8);
            #pragma unroll
            for (int ni = 0; ni < 4; ++ni)
                bfv[ni] = *(const bf16x8*)(Bs + (wn*64 + ni*16 + lr) * 64 + ks + lg*8);
            #pragma unroll
            for (int mi = 0; mi < 4; ++mi)
                #pragma unroll
                for (int ni = 0; ni < 4; ++ni)
                    acc[mi][ni] = __builtin_amdgcn_mfma_f32_16x16x32_bf16(
                        af[mi], bfv[ni], acc[mi][ni], 0, 0, 0);
        }
        __syncthreads();
    }

    // ---- tanh, write XV into Xs in A-layout (bf16, padded stride 136) ----
    #pragma unroll
    for (int mi = 0; mi < 4; ++mi)
        #pragma unroll
        for (int ni = 0; ni < 4; ++ni)
            #pragma unroll
            for (int j = 0; j < 4; ++j) {
                int m  = wm*64 + mi*16 + lg*4 + j;
                int k2 = wn*64 + ni*16 + lr;
                Xs[m * 136 + k2] = (bf16_t)tanh_fast(acc[mi][ni][j]);
            }

    // stage C^T padded (reg path; conflict-free reads at stride 136)
    const bf16_t* Ce = Cl + (size_t)e * RANK * RANK;
    #pragma unroll
    for (int i = 0; i < 8; ++i) {
        int q = tid + 256 * i;                        // 0..2047
        int row = q >> 4, c8 = (q & 15) << 3;
        bf16x8 v = *(const bf16x8*)(Ce + row * RANK + c8);
        *(bf16x8*)(Cs + row * 136 + c8) = v;
    }
    __syncthreads();

    // ---- phase 2: XC = XV @ C^T  (M=128, N=128, K=128) ----
    f32x4 acc2[4][4] = {};
    #pragma unroll
    for (int ks = 0; ks < 128; ks += 32) {
        bf16x8 af[4], bfv[4];
        #pragma unroll
        for (int mi = 0; mi < 4; ++mi)
            af[mi] = *(const bf16x8*)(Xs + (wm*64 + mi*16 + lr) * 136 + ks + lg*8);
        #pragma unroll
        for (int ni = 0; ni < 4; ++ni)
            bfv[ni] = *(const bf16x8*)(Cs + (wn*64 + ni*16 + lr) * 136 + ks + lg*8);
        #pragma unroll
        for (int mi = 0; mi < 4; ++mi)
            #pragma unroll
            for (int ni = 0; ni < 4; ++ni)
                acc2[mi][ni] = __builtin_amdgcn_mfma_f32_16x16x32_bf16(
                    af[mi], bfv[ni], acc2[mi][ni], 0, 0, 0);
    }

    // ---- tanh + global write of XC (bf16) ----
    #pragma unroll
    for (int mi = 0; mi < 4; ++mi)
        #pragma unroll
        for (int ni = 0; ni < 4; ++ni)
            #pragma unroll
            for (int j = 0; j < 4; ++j) {
                int m = wm*64 + mi*16 + lg*4 + j;
                int c = wn*64 + ni*16 + lr;
                XC[(size_t)(m0 + m) * DIM + e * RANK + c] =
                    (bf16_t)tanh_fast(acc2[mi][ni][j]);
            }
}

// ---------------- k2: out = xl + x0 * (XC @ Ucat + E*bias) ----------------
// grid (BATCH/128, DIM/128), block 256. Also writes bf16 shadow of out.

__global__ __launch_bounds__(256, 2)
void k2_u(const bf16_t* __restrict__ XC,   // (B, 512) bf16
          const bf16_t* __restrict__ Ul,   // [E][D][R] this layer
          const float* __restrict__ x0,    // (B, 512)
          const float* __restrict__ xl,    // (B, 512) layer input (f32)
          const float* __restrict__ bias,  // [D] this layer
          float* __restrict__ out,         // (B, 512) f32
          bf16_t* __restrict__ outb)       // (B, 512) bf16 shadow (may be null)
{
    const int m0   = blockIdx.x * 128;
    const int n0   = blockIdx.y * 128;
    const int tid  = threadIdx.x;
    const int lane = tid & 63;
    const int wave = tid >> 6;
    const int wm = wave >> 1, wn = wave & 1;
    const int lr = lane & 15;
    const int lg = lane >> 4;

    __shared__ __align__(16) char smem[32768];
    bf16_t* As = (bf16_t*)smem;              // [128][64] linear
    bf16_t* Bs = (bf16_t*)(smem + 16384);    // [128][64] linear

    f32x4 acc[4][4] = {};

    for (int kc = 0; kc < 512; kc += 64) {
        const int e  = kc >> 7;
        const int r0 = kc & 127;
        stage64(XC + (size_t)m0 * DIM + kc,                       DIM * 2,  As, tid);
        stage64(Ul + ((size_t)e * DIM + n0) * RANK + r0,          RANK * 2, Bs, tid);
        __syncthreads();
        #pragma unroll
        for (int ks = 0; ks < 64; ks += 32) {
            bf16x8 af[4], bfv[4];
            #pragma unroll
            for (int mi = 0; mi < 4; ++mi)
                af[mi] = *(const bf16x8*)(As + (wm*64 + mi*16 + lr) * 64 + ks + lg*8);
            #pragma unroll
            for (int ni = 0; ni < 4; ++ni)
                bfv[ni] = *(const bf16x8*)(Bs + (wn*64 + ni*16 + lr) * 64 + ks + lg*8);
            #pragma unroll
            for (int mi = 0; mi < 4; ++mi)
                #pragma unroll
                for (int ni = 0; ni < 4; ++ni)
                    acc[mi][ni] = __builtin_amdgcn_mfma_f32_16x16x32_bf16(
                        af[mi], bfv[ni], acc[mi][ni], 0, 0, 0);
        }
        __syncthreads();
    }

    // epilogue: out = xl + x0 * (acc + E*bias)   (gate == 1 exactly)
    #pragma unroll
    for (int ni = 0; ni < 4; ++ni) {
        int n = n0 + wn*64 + ni*16 + lr;
        float b4 = 4.0f * bias[n];
        #pragma unroll
        for (int mi = 0; mi < 4; ++mi)
            #pragma unroll
            for (int j = 0; j < 4; ++j) {
                int m = m0 + wm*64 + mi*16 + lg*4 + j;
                size_t idx = (size_t)m * DIM + n;
                float o = xl[idx] + x0[idx] * (acc[mi][ni][j] + b4);
                out[idx] = o;
                if (outb) outb[idx] = (bf16_t)o;
            }
    }
}

// ---------------- host ----------------

extern "C" void kernel_launch(void* const* d_in, const int* in_sizes, int n_in,
                              void* d_out, int out_size, void* d_ws, size_t ws_size,
                              hipStream_t stream) {
    const float* x  = (const float*)d_in[0];   // (B, D)
    const float* Us = (const float*)d_in[1];   // (L, E, D, R)
    const float* Cw = (const float*)d_in[2];   // (L, E, R, R)
    const float* Vs = (const float*)d_in[3];   // (L, E, D, R)
    // d_in[4] = G: softmax over singleton axis == 1.0 -> unused
    const float* bb = (const float*)d_in[5];   // (L, D)
    float* out = (float*)d_out;

    const int nV = NLAYER * NEXP * DIM * RANK;   // 786432
    const int nC = NLAYER * NEXP * RANK * RANK;  // 196608
    const int nX = BATCH * DIM;                  // 8388608

    char* w = (char*)d_ws;
    bf16_t* Vt = (bf16_t*)w;                                     // [L][E][R][D]
    bf16_t* Ub = (bf16_t*)(w + (size_t)nV * 2);                  // [L][E][D][R]
    bf16_t* Cb = (bf16_t*)(w + (size_t)nV * 4);                  // [L][E][R][R]
    bf16_t* XC = (bf16_t*)(w + (size_t)nV * 4 + (size_t)nC * 2); // (B, 512) bf16
    bf16_t* xb = XC + (size_t)nX;                                // (B, 512) bf16 xl shadow

    transpose_v<<<nV / 256, 256, 0, stream>>>(Vs, Vt);
    convert8<<<(nV / 8 + 255) / 256, 256, 0, stream>>>(Us, Ub, nV / 8);
    convert8<<<(nC / 8 + 255) / 256, 256, 0, stream>>>(Cw, Cb, nC / 8);
    convert8<<<(nX / 8 + 255) / 256, 256, 0, stream>>>(x, xb, nX / 8);

    for (int l = 0; l < NLAYER; ++l) {
        const float* xl = (l == 0) ? x : out;
        k1_vc<<<dim3(BATCH / 128, NEXP), 256, 0, stream>>>(
            xb,
            Vt + (size_t)l * NEXP * RANK * DIM,
            Cb + (size_t)l * NEXP * RANK * RANK,
            XC);
        k2_u<<<dim3(BATCH / 128, DIM / 128), 256, 0, stream>>>(
            XC,
            Ub + (size_t)l * NEXP * DIM * RANK,
            x, xl, bb + (size_t)l * DIM,
            out,
            (l == NLAYER - 1) ? (bf16_t*)nullptr : xb);
    }
}

// Round 3
// 190.103 us; speedup vs baseline: 1.0778x; 1.0778x over previous
//
#include <hip/hip_runtime.h>
#include <hip/hip_bf16.h>

// Problem constants
#define BATCH  16384
#define DIM    512
#define NLAYER 3
#define NEXP   4
#define RANK   128

typedef __bf16 bf16_t;
typedef bf16_t bf16x8 __attribute__((ext_vector_type(8)));
typedef float  f32x4  __attribute__((ext_vector_type(4)));

__device__ __forceinline__ float tanh_fast(float x) {
    float e = __expf(2.0f * x);
    return 1.0f - 2.0f * __builtin_amdgcn_rcpf(e + 1.0f);
}

// 16B-slot XOR swizzle within a row (bits 4..6) -> breaks same-bank row strides
__device__ __forceinline__ int swz(int row, int byte_in_row) {
    return byte_in_row ^ ((row & 7) << 4);
}

// Stage a [128 rows][64 cols] bf16 tile (16 KB) global->LDS via async
// global_load_lds. LDS dest is linear; the global SOURCE column is
// pre-swizzled so readers use swz() (both-sides-or-neither rule, m173).
// 512-thread block: each wave stages 2x 1KB chunks.
__device__ __forceinline__ void stage_tile(const bf16_t* __restrict__ g,
                                           int gstride_b, bf16_t* l, int tid) {
    const int lane = tid & 63, wave = tid >> 6;
    #pragma unroll
    for (int i = 0; i < 2; ++i) {
        int chunk = i * 8 + wave;                 // 0..15
        int o     = chunk * 1024 + lane * 16;     // byte offset in 16KB tile
        int row   = o >> 7;                       // 128 B per LDS row
        int cbg   = swz(row, o & 127);            // swizzled source column
        const char* gp = (const char*)g + (size_t)row * gstride_b + cbg;
        char* lp = (char*)l + chunk * 1024;       // wave-uniform; HW adds lane*16
        __builtin_amdgcn_global_load_lds(
            (const __attribute__((address_space(1))) void*)gp,
            (__attribute__((address_space(3))) void*)lp, 16, 0, 0);
    }
}

// swizzled LDS bf16x8 fragment read
__device__ __forceinline__ bf16x8 ldsr(const bf16_t* base, int row,
                                       int rowstride_b, int kb) {
    const char* p = (const char*)base + row * rowstride_b + swz(row, kb);
    return *(const bf16x8*)p;
}

__device__ __forceinline__ void ldsw16(bf16_t* base, int row, int rowstride_b,
                                       int colbyte, bf16_t v) {
    *(bf16_t*)((char*)base + row * rowstride_b + swz(row, colbyte)) = v;
}

// ---------------- prep kernels ----------------

__global__ void convert8(const float* __restrict__ in,
                         bf16_t* __restrict__ out, int n8) {
    int i = blockIdx.x * 256 + threadIdx.x;
    if (i >= n8) return;
    float4 a = *(const float4*)(in + (size_t)i * 8);
    float4 b = *(const float4*)(in + (size_t)i * 8 + 4);
    bf16x8 v = { (bf16_t)a.x, (bf16_t)a.y, (bf16_t)a.z, (bf16_t)a.w,
                 (bf16_t)b.x, (bf16_t)b.y, (bf16_t)b.z, (bf16_t)b.w };
    *(bf16x8*)(out + (size_t)i * 8) = v;
}

// Vt[le][r][d] = Vs[le][d][r]
__global__ void transpose_v(const float* __restrict__ Vs,
                            bf16_t* __restrict__ Vt) {
    int i = blockIdx.x * 256 + threadIdx.x;      // < 12*128*512
    int d  = i & (DIM - 1);
    int r  = (i >> 9) & (RANK - 1);
    int le = i >> 16;
    Vt[i] = (bf16_t)Vs[((size_t)le * DIM + d) * RANK + r];
}

// ---------------- fused 3-layer kernel ----------------
// grid 256 blocks (64 rows each) x 512 threads (8 waves, 2x4 wave grid).
// Residual xl stays f32 in registers; bf16 copy in LDS feeds MFMA;
// XV/XC live only in LDS; weights streamed via swizzled global_load_lds.

__global__ __launch_bounds__(512, 1)
void fused3(const float* __restrict__ x,    // (B, 512) f32 (= x0)
            const bf16_t* __restrict__ Vt,  // [L][E][R][D]
            const bf16_t* __restrict__ Ub,  // [L][E][D][R]
            const bf16_t* __restrict__ Cb,  // [L][E][R][R]
            const float* __restrict__ bb,   // [L][D]
            float* __restrict__ out)        // (B, 512) f32
{
    __shared__ __align__(16) char smem[114688];          // 112 KB
    bf16_t* xlb = (bf16_t*)smem;                 // [64][512] bf16, rows 1024 B, swz
    bf16_t* xvb = (bf16_t*)(smem + 65536);       // [64][128] bf16, rows 256 B, swz
    bf16_t* bs0 = (bf16_t*)(smem + 81920);       // [128][64] staging, rows 128 B, swz
    bf16_t* bs1 = (bf16_t*)(smem + 98304);

    const int tid  = threadIdx.x;
    const int lane = tid & 63;
    const int wm   = (tid >> 6) >> 2;    // 0..1  (32-row half)
    const int wn   = (tid >> 6) & 3;     // 0..3  (32-col group)
    const int lr   = lane & 15;
    const int lg   = lane >> 4;
    const int m0   = blockIdx.x * 64;

    // ownership: row(mi,j) = wm*32 + mi*16 + lg*4 + j   (local, + m0 global)
    //            col(ni)   = (ni>>1)*128 + wn*32 + (ni&1)*16 + lr
    f32x4 xlf[2][8];

    // ---- init: load x fragments (f32), seed residual, write bf16 xlb ----
    #pragma unroll
    for (int mi = 0; mi < 2; ++mi)
        #pragma unroll
        for (int ni = 0; ni < 8; ++ni) {
            int col = ((ni >> 1) << 7) + wn * 32 + ((ni & 1) << 4) + lr;
            #pragma unroll
            for (int j = 0; j < 4; ++j) {
                int row = wm * 32 + mi * 16 + lg * 4 + j;
                float v = x[(size_t)(m0 + row) * DIM + col];
                xlf[mi][ni][j] = v;
                ldsw16(xlb, row, 1024, col * 2, (bf16_t)v);
            }
        }
    __syncthreads();

    for (int l = 0; l < NLAYER; ++l) {
        const bf16_t* Vl = Vt + (size_t)l * NEXP * RANK * DIM;
        const bf16_t* Ul = Ub + (size_t)l * NEXP * DIM * RANK;
        const bf16_t* Cl = Cb + (size_t)l * NEXP * RANK * RANK;

        f32x4 acc[2][8] = {};                    // xu accumulator (all experts)

        for (int e = 0; e < NEXP; ++e) {
            const bf16_t* Ve = Vl + (size_t)e * RANK * DIM;
            const bf16_t* Ce = Cl + (size_t)e * RANK * RANK;
            const bf16_t* Ue = Ul + (size_t)e * DIM * RANK;

            // ---- phase 1: XV = xl @ V_e  (64x128, K=512), 2-phase dbuf ----
            f32x4 acc2[2][2] = {};
            stage_tile(Ve, DIM * 2, bs0, tid);
            __syncthreads();
            #pragma unroll
            for (int st = 0; st < 8; ++st) {
                bf16_t* cur = (st & 1) ? bs1 : bs0;
                bf16_t* nxt = (st & 1) ? bs0 : bs1;
                if (st < 7) stage_tile(Ve + (st + 1) * 64, DIM * 2, nxt, tid);
                #pragma unroll
                for (int ks = 0; ks < 64; ks += 32) {
                    bf16x8 af[2], bfv[2];
                    #pragma unroll
                    for (int mi = 0; mi < 2; ++mi)
                        af[mi] = ldsr(xlb, wm*32 + mi*16 + lr, 1024,
                                      st*128 + ks*2 + lg*16);
                    #pragma unroll
                    for (int ni = 0; ni < 2; ++ni)
                        bfv[ni] = ldsr(cur, wn*32 + ni*16 + lr, 128,
                                       ks*2 + lg*16);
                    #pragma unroll
                    for (int mi = 0; mi < 2; ++mi)
                        #pragma unroll
                        for (int ni = 0; ni < 2; ++ni)
                            acc2[mi][ni] = __builtin_amdgcn_mfma_f32_16x16x32_bf16(
                                af[mi], bfv[ni], acc2[mi][ni], 0, 0, 0);
                }
                __syncthreads();
            }

            // tanh -> XV into xvb
            #pragma unroll
            for (int mi = 0; mi < 2; ++mi)
                #pragma unroll
                for (int ni = 0; ni < 2; ++ni)
                    #pragma unroll
                    for (int j = 0; j < 4; ++j) {
                        int row = wm*32 + mi*16 + lg*4 + j;
                        int c   = wn*32 + ni*16 + lr;
                        ldsw16(xvb, row, 256, c * 2,
                               (bf16_t)tanh_fast(acc2[mi][ni][j]));
                    }
            __syncthreads();

            // ---- phase 2: XC = XV @ C_e^T  (64x128, K=128) ----
            stage_tile(Ce,      RANK * 2, bs0, tid);   // s = 0..63
            stage_tile(Ce + 64, RANK * 2, bs1, tid);   // s = 64..127
            __syncthreads();
            f32x4 acc3[2][2] = {};
            #pragma unroll
            for (int k4 = 0; k4 < 4; ++k4) {           // ks = k4*32
                bf16_t* half = (k4 < 2) ? bs0 : bs1;
                int klocal = (k4 & 1) * 64;            // bytes within half
                bf16x8 af[2], bfv[2];
                #pragma unroll
                for (int mi = 0; mi < 2; ++mi)
                    af[mi] = ldsr(xvb, wm*32 + mi*16 + lr, 256, k4*64 + lg*16);
                #pragma unroll
                for (int ni = 0; ni < 2; ++ni)
                    bfv[ni] = ldsr(half, wn*32 + ni*16 + lr, 128, klocal + lg*16);
                #pragma unroll
                for (int mi = 0; mi < 2; ++mi)
                    #pragma unroll
                    for (int ni = 0; ni < 2; ++ni)
                        acc3[mi][ni] = __builtin_amdgcn_mfma_f32_16x16x32_bf16(
                            af[mi], bfv[ni], acc3[mi][ni], 0, 0, 0);
            }
            __syncthreads();

            // tanh -> XC overwrites xvb
            #pragma unroll
            for (int mi = 0; mi < 2; ++mi)
                #pragma unroll
                for (int ni = 0; ni < 2; ++ni)
                    #pragma unroll
                    for (int j = 0; j < 4; ++j) {
                        int row = wm*32 + mi*16 + lg*4 + j;
                        int c   = wn*32 + ni*16 + lr;
                        ldsw16(xvb, row, 256, c * 2,
                               (bf16_t)tanh_fast(acc3[mi][ni][j]));
                    }
            __syncthreads();

            // ---- phase 3: xu += XC @ U_e^T  (64x512, K=128), 2-phase dbuf ----
            stage_tile(Ue, RANK * 2, bs0, tid);        // nc0, r 0..63
            __syncthreads();
            #pragma unroll
            for (int h = 0; h < 8; ++h) {              // half-tiles: nc = h>>1
                bf16_t* cur = (h & 1) ? bs1 : bs0;
                bf16_t* nxt = (h & 1) ? bs0 : bs1;
                if (h < 7) {
                    int h1 = h + 1;
                    stage_tile(Ue + (size_t)(h1 >> 1) * 128 * RANK + (h1 & 1) * 64,
                               RANK * 2, nxt, tid);
                }
                const int nc = h >> 1, part = h & 1;
                #pragma unroll
                for (int ks = 0; ks < 64; ks += 32) {
                    bf16x8 af[2], bfv[2];
                    #pragma unroll
                    for (int mi = 0; mi < 2; ++mi)
                        af[mi] = ldsr(xvb, wm*32 + mi*16 + lr, 256,
                                      part*128 + ks*2 + lg*16);
                    #pragma unroll
                    for (int ni = 0; ni < 2; ++ni)
                        bfv[ni] = ldsr(cur, wn*32 + ni*16 + lr, 128,
                                       ks*2 + lg*16);
                    #pragma unroll
                    for (int mi = 0; mi < 2; ++mi)
                        #pragma unroll
                        for (int ni = 0; ni < 2; ++ni)
                            acc[mi][nc*2 + ni] = __builtin_amdgcn_mfma_f32_16x16x32_bf16(
                                af[mi], bfv[ni], acc[mi][nc*2 + ni], 0, 0, 0);
                }
                __syncthreads();
            }
        } // experts

        // ---- residual update: xl += x0 * (xu + E*bias)  (gate == 1) ----
        const float* bl = bb + l * DIM;
        #pragma unroll
        for (int ni = 0; ni < 8; ++ni) {
            int col = ((ni >> 1) << 7) + wn * 32 + ((ni & 1) << 4) + lr;
            float b4 = 4.0f * bl[col];
            #pragma unroll
            for (int mi = 0; mi < 2; ++mi)
                #pragma unroll
                for (int j = 0; j < 4; ++j) {
                    int row = wm*32 + mi*16 + lg*4 + j;
                    float x0v = x[(size_t)(m0 + row) * DIM + col];
                    xlf[mi][ni][j] += x0v * (acc[mi][ni][j] + b4);
                }
        }

        if (l < NLAYER - 1) {
            // rewrite bf16 xl copy for next layer (all waves past ph3 barrier)
            #pragma unroll
            for (int mi = 0; mi < 2; ++mi)
                #pragma unroll
                for (int ni = 0; ni < 8; ++ni) {
                    int col = ((ni >> 1) << 7) + wn * 32 + ((ni & 1) << 4) + lr;
                    #pragma unroll
                    for (int j = 0; j < 4; ++j) {
                        int row = wm*32 + mi*16 + lg*4 + j;
                        ldsw16(xlb, row, 1024, col * 2, (bf16_t)xlf[mi][ni][j]);
                    }
                }
            __syncthreads();
        }
    } // layers

    // ---- epilogue: write final residual ----
    #pragma unroll
    for (int mi = 0; mi < 2; ++mi)
        #pragma unroll
        for (int ni = 0; ni < 8; ++ni) {
            int col = ((ni >> 1) << 7) + wn * 32 + ((ni & 1) << 4) + lr;
            #pragma unroll
            for (int j = 0; j < 4; ++j) {
                int row = wm*32 + mi*16 + lg*4 + j;
                out[(size_t)(m0 + row) * DIM + col] = xlf[mi][ni][j];
            }
        }
}

// ---------------- host ----------------

extern "C" void kernel_launch(void* const* d_in, const int* in_sizes, int n_in,
                              void* d_out, int out_size, void* d_ws, size_t ws_size,
                              hipStream_t stream) {
    const float* x  = (const float*)d_in[0];   // (B, D)
    const float* Us = (const float*)d_in[1];   // (L, E, D, R)
    const float* Cw = (const float*)d_in[2];   // (L, E, R, R)
    const float* Vs = (const float*)d_in[3];   // (L, E, D, R)
    // d_in[4] = G: softmax over singleton axis == 1.0 -> unused
    const float* bb = (const float*)d_in[5];   // (L, D)
    float* out = (float*)d_out;

    const int nV = NLAYER * NEXP * DIM * RANK;   // 786432
    const int nC = NLAYER * NEXP * RANK * RANK;  // 196608

    char* w = (char*)d_ws;
    bf16_t* Vt = (bf16_t*)w;                      // [L][E][R][D]
    bf16_t* Ub = (bf16_t*)(w + (size_t)nV * 2);   // [L][E][D][R]
    bf16_t* Cb = (bf16_t*)(w + (size_t)nV * 4);   // [L][E][R][R]

    transpose_v<<<nV / 256, 256, 0, stream>>>(Vs, Vt);
    convert8<<<(nV / 8 + 255) / 256, 256, 0, stream>>>(Us, Ub, nV / 8);
    convert8<<<(nC / 8 + 255) / 256, 256, 0, stream>>>(Cw, Cb, nC / 8);

    fused3<<<BATCH / 64, 512, 0, stream>>>(x, Vt, Ub, Cb, bb, out);
}